// Round 3
// baseline (1806.672 us; speedup 1.0000x reference)
//
#include <hip/hip_runtime.h>
#include <hip/hip_bf16.h>

#define NEG_SLOPE 0.2f

typedef __attribute__((ext_vector_type(8))) short bf16x8;
typedef __attribute__((ext_vector_type(4))) float f32x4;

// ---------------------------------------------------------------------------
// CSR build
// ---------------------------------------------------------------------------
__global__ void hist_kernel(const int* __restrict__ dst, int* __restrict__ cnt, int E) {
    int e = blockIdx.x * 256 + threadIdx.x;
    if (e < E) atomicAdd(&cnt[dst[e]], 1);
}

__global__ void scan_s1(const int* __restrict__ cnt, int* __restrict__ excl,
                        int* __restrict__ totals, int N) {
    __shared__ int lds[256];
    int t = threadIdx.x;
    int i = blockIdx.x * 256 + t;
    int v = (i < N) ? cnt[i] : 0;
    lds[t] = v;
    __syncthreads();
    #pragma unroll
    for (int off = 1; off < 256; off <<= 1) {
        int add = (t >= off) ? lds[t - off] : 0;
        __syncthreads();
        lds[t] += add;
        __syncthreads();
    }
    if (i < N) excl[i] = lds[t] - v;
    if (t == 255) totals[blockIdx.x] = lds[255];
}

__global__ void scan_s2(int* __restrict__ totals, int nb) {
    __shared__ int lds[256];
    int t = threadIdx.x;
    int v = (t < nb) ? totals[t] : 0;
    lds[t] = v;
    __syncthreads();
    #pragma unroll
    for (int off = 1; off < 256; off <<= 1) {
        int add = (t >= off) ? lds[t - off] : 0;
        __syncthreads();
        lds[t] += add;
        __syncthreads();
    }
    if (t < nb) totals[t] = lds[t] - v;   // exclusive over block totals
}

__global__ void scan_s3(int* __restrict__ row_ptr, const int* __restrict__ totals,
                        int* __restrict__ cursor, int N, int E) {
    int i = blockIdx.x * 256 + threadIdx.x;
    if (i < N) {
        int v = row_ptr[i] + totals[blockIdx.x];
        row_ptr[i] = v;
        cursor[i] = v;
    }
    if (i == 0) row_ptr[N] = E;
}

__global__ void scatter_kernel(const int* __restrict__ src, const int* __restrict__ dst,
                               int* __restrict__ cursor, int* __restrict__ col_src,
                               int* __restrict__ col_dst, int* __restrict__ col_eid, int E) {
    int e = blockIdx.x * 256 + threadIdx.x;
    if (e < E) {
        int d = dst[e];
        int pos = atomicAdd(&cursor[d], 1);
        col_src[pos] = src[e];
        col_dst[pos] = d;
        col_eid[pos] = e;
    }
}

// ---------------------------------------------------------------------------
// Pack We (fp32 [32,256]) into MFMA A-fragment order, bf16 hi + lo parts.
// WeP layout: [layer][part][tile][lane][8] shorts; A[m=lane&15][k=(lane>>4)*8+j]
// layer stride = 16384 shorts, lo part at +8192 shorts.
// ---------------------------------------------------------------------------
__global__ void pack_we(const float* __restrict__ We0, const float* __restrict__ We1,
                        unsigned short* __restrict__ WeP) {
    int t = blockIdx.x * 256 + threadIdx.x;
    if (t >= 4096) return;
    int layer = t >> 11;
    int part  = (t >> 10) & 1;
    int tile  = (t >> 6) & 15;
    int lane  = t & 63;
    const float* We = layer ? We1 : We0;
    int ch = tile * 16 + (lane & 15);
    int kb = (lane >> 4) * 8;
    union { unsigned short u[8]; uint4 v; } out;
    #pragma unroll
    for (int j = 0; j < 8; ++j) {
        float w = We[(size_t)(kb + j) * 256 + ch];
        __hip_bfloat16 hi = __float2bfloat16(w);
        if (part == 0) {
            out.u[j] = *(unsigned short*)&hi;
        } else {
            float lo = w - __bfloat162float(hi);
            __hip_bfloat16 lh = __float2bfloat16(lo);
            out.u[j] = *(unsigned short*)&lh;
        }
    }
    *(uint4*)(WeP + (size_t)t * 8) = out.v;
}

// ---------------------------------------------------------------------------
// Pass 1: per-edge attention logits [E,4] in CSR slot order.
// One wave handles 16 edges. ea computed via 3-term hi/lo bf16 MFMA split
// (fp32-accurate); xl/xr gathered per 16-channel tile; att folded; 4-lane
// cross-q shuffle reduce -> logits.
// ---------------------------------------------------------------------------
__global__ __launch_bounds__(256, 2) void logit_kernel(
    const float* __restrict__ xlxr,       // [N,512]
    const float* __restrict__ edge_attr,  // [E,32]
    const int* __restrict__ col_src,      // [E]
    const int* __restrict__ col_dst,      // [E]
    const int* __restrict__ col_eid,      // [E]
    const unsigned short* __restrict__ WePl, // this layer's frags (hi @0, lo @+8192)
    const float* __restrict__ att,        // [256]
    float* __restrict__ logits,           // [E,4]
    int E)
{
    const int lane  = threadIdx.x & 63;
    const int gw    = blockIdx.x * 4 + (threadIdx.x >> 6);
    const int nw    = gridDim.x * 4;
    const int q     = lane >> 4;
    const int e_sub = lane & 15;
    const int kb    = q * 8;

    bf16x8 Ahi[16], Alo[16];
    #pragma unroll
    for (int t = 0; t < 16; ++t) {
        Ahi[t] = *(const bf16x8*)(WePl + ((size_t)t * 64 + lane) * 8);
        Alo[t] = *(const bf16x8*)(WePl + 8192 + ((size_t)t * 64 + lane) * 8);
    }

    const int nb = (E + 15) >> 4;
    for (int b = gw; b < nb; b += nw) {
        const int slot = b * 16 + e_sub;
        const int sc   = min(slot, E - 1);
        const int eid  = col_eid[sc];
        const int srcn = col_src[sc];
        const int dstn = col_dst[sc];

        const float* ap = edge_attr + (size_t)eid * 32 + kb;
        float4 v0 = *(const float4*)ap;
        float4 v1 = *(const float4*)(ap + 4);
        float vv[8] = {v0.x, v0.y, v0.z, v0.w, v1.x, v1.y, v1.z, v1.w};
        union { bf16x8 v; unsigned short u[8]; } bh, bl;
        #pragma unroll
        for (int i = 0; i < 8; ++i) {
            __hip_bfloat16 h = __float2bfloat16(vv[i]);
            bh.u[i] = *(unsigned short*)&h;
            float r = vv[i] - __bfloat162float(h);
            __hip_bfloat16 h2 = __float2bfloat16(r);
            bl.u[i] = *(unsigned short*)&h2;
        }

        const float* xlp = xlxr + (size_t)srcn * 512 + q * 4;
        const float* xrp = xlxr + (size_t)dstn * 512 + 256 + q * 4;

        float lph[4] = {0.f, 0.f, 0.f, 0.f};
        #pragma unroll
        for (int t = 0; t < 16; ++t) {
            f32x4 acc = {0.f, 0.f, 0.f, 0.f};
            acc = __builtin_amdgcn_mfma_f32_16x16x32_bf16(Ahi[t], bh.v, acc, 0, 0, 0);
            acc = __builtin_amdgcn_mfma_f32_16x16x32_bf16(Ahi[t], bl.v, acc, 0, 0, 0);
            acc = __builtin_amdgcn_mfma_f32_16x16x32_bf16(Alo[t], bh.v, acc, 0, 0, 0);
            const float4 xl4 = *(const float4*)(xlp + t * 16);
            const float4 xr4 = *(const float4*)(xrp + t * 16);
            const float4 at4 = *(const float4*)(att + t * 16 + q * 4);
            float z0 = acc[0] + xl4.x + xr4.x; z0 = (z0 > 0.f) ? z0 : NEG_SLOPE * z0;
            float z1 = acc[1] + xl4.y + xr4.y; z1 = (z1 > 0.f) ? z1 : NEG_SLOPE * z1;
            float z2 = acc[2] + xl4.z + xr4.z; z2 = (z2 > 0.f) ? z2 : NEG_SLOPE * z2;
            float z3 = acc[3] + xl4.w + xr4.w; z3 = (z3 > 0.f) ? z3 : NEG_SLOPE * z3;
            float s = z0 * at4.x;
            s = fmaf(z1, at4.y, s);
            s = fmaf(z2, at4.z, s);
            s = fmaf(z3, at4.w, s);
            lph[t >> 2] += s;
        }
        #pragma unroll
        for (int h = 0; h < 4; ++h) {
            lph[h] += __shfl_xor(lph[h], 16, 64);
            lph[h] += __shfl_xor(lph[h], 32, 64);
        }
        if (q == 0 && slot < E) {
            float4 o = make_float4(lph[0], lph[1], lph[2], lph[3]);
            *(float4*)(logits + (size_t)slot * 4) = o;
        }
    }
}

// ---------------------------------------------------------------------------
// Pass 2: aggregation. One wave per node, lane owns channels 4l..4l+3
// (head = l>>4). Two loops over the node's CSR edge range: max, then
// exp/denom/weighted xl accumulate. Fused bias + ReLU.
// ---------------------------------------------------------------------------
__global__ __launch_bounds__(256) void aggregate_kernel(
    const float* __restrict__ xlxr,     // [N,512]
    const float* __restrict__ logits,   // [E,4] CSR order
    const int* __restrict__ col_src,    // [E]
    const int* __restrict__ row_ptr,    // [N+1]
    const float* __restrict__ bias,     // [256]
    float* __restrict__ hout, int N)
{
    const int n = blockIdx.x * 4 + (threadIdx.x >> 6);
    if (n >= N) return;
    const int l = threadIdx.x & 63;
    const int h = l >> 4;
    const int ch0 = l * 4;

    const int e0 = row_ptr[n], e1 = row_ptr[n + 1];

    float mxh = -3.0e38f;
    for (int j = e0; j < e1; ++j)
        mxh = fmaxf(mxh, logits[(size_t)j * 4 + h]);

    float denom = 0.f;
    float4 acc = make_float4(0.f, 0.f, 0.f, 0.f);
    for (int j = e0; j < e1; ++j) {
        const float lh = logits[(size_t)j * 4 + h];
        const float p = __expf(lh - mxh);
        denom += p;
        const int srcn = col_src[j];
        const float4 xl = *(const float4*)(xlxr + (size_t)srcn * 512 + ch0);
        acc.x = fmaf(p, xl.x, acc.x);
        acc.y = fmaf(p, xl.y, acc.y);
        acc.z = fmaf(p, xl.z, acc.z);
        acc.w = fmaf(p, xl.w, acc.w);
    }

    const float inv = (e1 > e0) ? 1.0f / denom : 0.f;
    const float4 b4 = *(const float4*)(bias + ch0);
    float4 o;
    o.x = fmaxf(fmaf(acc.x, inv, b4.x), 0.f);
    o.y = fmaxf(fmaf(acc.y, inv, b4.y), 0.f);
    o.z = fmaxf(fmaf(acc.z, inv, b4.z), 0.f);
    o.w = fmaxf(fmaf(acc.w, inv, b4.w), 0.f);
    *(float4*)(hout + (size_t)n * 256 + ch0) = o;
}

// ---------------------------------------------------------------------------
// Fused GEMM: C[M,512] = A[M,K] @ [Wl | Wr] + [bl | br], 128x128x16 tile,
// 256 threads, 8x8 per thread (two 4x4 quads per dim at +64 offsets).
// ---------------------------------------------------------------------------
__global__ __launch_bounds__(256) void gemm_xlxr128(
    const float* __restrict__ A, int M, int K,
    const float* __restrict__ Wl, const float* __restrict__ bl,
    const float* __restrict__ Wr, const float* __restrict__ br,
    float* __restrict__ C)
{
    constexpr int BM = 128, BN = 128, BK = 16;
    __shared__ float As[BK][BM];   // transposed A tile
    __shared__ float Bs[BK][BN];

    const int tid = threadIdx.x;
    const int m0 = blockIdx.x * BM;
    const int n0 = blockIdx.y * BN;

    const float* W; const float* bv; int nc0;
    if (n0 < 256) { W = Wl; bv = bl; nc0 = n0; }
    else          { W = Wr; bv = br; nc0 = n0 - 256; }

    const int ty = tid >> 4;
    const int tx = tid & 15;

    float acc[2][4][2][4];
    #pragma unroll
    for (int ri = 0; ri < 2; ri++)
        #pragma unroll
        for (int i = 0; i < 4; i++)
            #pragma unroll
            for (int ci = 0; ci < 2; ci++)
                #pragma unroll
                for (int j = 0; j < 4; j++) acc[ri][i][ci][j] = 0.f;

    const int arow = tid >> 1;
    const int akq  = (tid & 1) * 8;
    const int brow = tid >> 4;
    const int bcq  = (tid & 15) * 8;

    const int nKt = K / BK;
    for (int kt = 0; kt < nKt; ++kt) {
        const int k0 = kt * BK;
        {
            int gm = m0 + arow;
            float4 a0 = make_float4(0.f, 0.f, 0.f, 0.f);
            float4 a1 = make_float4(0.f, 0.f, 0.f, 0.f);
            if (gm < M) {
                a0 = *(const float4*)(A + (size_t)gm * K + k0 + akq);
                a1 = *(const float4*)(A + (size_t)gm * K + k0 + akq + 4);
            }
            As[akq + 0][arow] = a0.x;
            As[akq + 1][arow] = a0.y;
            As[akq + 2][arow] = a0.z;
            As[akq + 3][arow] = a0.w;
            As[akq + 4][arow] = a1.x;
            As[akq + 5][arow] = a1.y;
            As[akq + 6][arow] = a1.z;
            As[akq + 7][arow] = a1.w;
        }
        {
            const float* wp = W + (size_t)(k0 + brow) * 256 + nc0 + bcq;
            *(float4*)&Bs[brow][bcq]     = *(const float4*)wp;
            *(float4*)&Bs[brow][bcq + 4] = *(const float4*)(wp + 4);
        }
        __syncthreads();
        #pragma unroll
        for (int kk = 0; kk < BK; ++kk) {
            float a[2][4], b[2][4];
            *(float4*)&a[0][0] = *(const float4*)&As[kk][ty * 4];
            *(float4*)&a[1][0] = *(const float4*)&As[kk][ty * 4 + 64];
            *(float4*)&b[0][0] = *(const float4*)&Bs[kk][tx * 4];
            *(float4*)&b[1][0] = *(const float4*)&Bs[kk][tx * 4 + 64];
            #pragma unroll
            for (int ri = 0; ri < 2; ri++)
                #pragma unroll
                for (int i = 0; i < 4; i++)
                    #pragma unroll
                    for (int ci = 0; ci < 2; ci++)
                        #pragma unroll
                        for (int j = 0; j < 4; j++)
                            acc[ri][i][ci][j] = fmaf(a[ri][i], b[ci][j], acc[ri][i][ci][j]);
        }
        __syncthreads();
    }

    float bvals[2][4];
    #pragma unroll
    for (int ci = 0; ci < 2; ci++)
        #pragma unroll
        for (int j = 0; j < 4; j++)
            bvals[ci][j] = bv[nc0 + tx * 4 + ci * 64 + j];

    #pragma unroll
    for (int ri = 0; ri < 2; ri++)
        #pragma unroll
        for (int i = 0; i < 4; i++) {
            int gm = m0 + ty * 4 + ri * 64 + i;
            if (gm < M) {
                #pragma unroll
                for (int ci = 0; ci < 2; ci++) {
                    float4 o;
                    o.x = acc[ri][i][ci][0] + bvals[ci][0];
                    o.y = acc[ri][i][ci][1] + bvals[ci][1];
                    o.z = acc[ri][i][ci][2] + bvals[ci][2];
                    o.w = acc[ri][i][ci][3] + bvals[ci][3];
                    *(float4*)(C + (size_t)gm * 512 + n0 + tx * 4 + ci * 64) = o;
                }
            }
        }
}

// ---------------------------------------------------------------------------
// Final projection: out[n] = h[n,:] @ W_out + b_out. One wave per node.
// ---------------------------------------------------------------------------
__global__ __launch_bounds__(256) void final_out_kernel(
    const float* __restrict__ h, const float* __restrict__ Wout,
    const float* __restrict__ bout, float* __restrict__ out, int N)
{
    const int wid  = threadIdx.x >> 6;
    const int lane = threadIdx.x & 63;
    const int n = blockIdx.x * 4 + wid;
    if (n >= N) return;
    float s = 0.f;
    #pragma unroll
    for (int q = 0; q < 4; ++q) {
        int cidx = lane + q * 64;
        s = fmaf(h[(size_t)n * 256 + cidx], Wout[cidx], s);
    }
    #pragma unroll
    for (int off = 32; off > 0; off >>= 1)
        s += __shfl_xor(s, off, 64);
    if (lane == 0) out[n] = s + bout[0];
}

// ---------------------------------------------------------------------------
extern "C" void kernel_launch(void* const* d_in, const int* in_sizes, int n_in,
                              void* d_out, int out_size, void* d_ws, size_t ws_size,
                              hipStream_t stream) {
    const float* x         = (const float*)d_in[0];
    const int*   edge_idx  = (const int*)d_in[1];
    const float* edge_attr = (const float*)d_in[2];
    const float* W_l0 = (const float*)d_in[3];
    const float* b_l0 = (const float*)d_in[4];
    const float* W_r0 = (const float*)d_in[5];
    const float* b_r0 = (const float*)d_in[6];
    const float* W_e0 = (const float*)d_in[7];
    const float* att0 = (const float*)d_in[8];
    const float* bias0= (const float*)d_in[9];
    const float* W_l1 = (const float*)d_in[10];
    const float* b_l1 = (const float*)d_in[11];
    const float* W_r1 = (const float*)d_in[12];
    const float* b_r1 = (const float*)d_in[13];
    const float* W_e1 = (const float*)d_in[14];
    const float* att1 = (const float*)d_in[15];
    const float* bias1= (const float*)d_in[16];
    const float* W_out= (const float*)d_in[17];
    const float* b_out= (const float*)d_in[18];

    const int N = in_sizes[0] / 512;      // 50000
    const int E = in_sizes[1] / 2;        // 800000

    const int* src = edge_idx;
    const int* dst = edge_idx + E;

    // workspace layout (~176.6 MB total)
    char* ws = (char*)d_ws;
    size_t off = 0;
    float* bufA   = (float*)(ws + off); off += (size_t)N * 512 * 4;   // 102.4 MB
    float* bufB   = (float*)(ws + off); off += (size_t)N * 256 * 4;   //  51.2 MB
    float* logits = (float*)(ws + off); off += (size_t)E * 4 * 4;     //  12.8 MB
    int* row_ptr  = (int*)(ws + off);   off += (((size_t)(N + 1) * 4 + 255) & ~(size_t)255);
    int* cursor   = (int*)(ws + off);   off += (((size_t)N * 4 + 255) & ~(size_t)255);
    int* col_src  = (int*)(ws + off);   off += (size_t)E * 4;
    int* col_dst  = (int*)(ws + off);   off += (size_t)E * 4;
    int* col_eid  = (int*)(ws + off);   off += (size_t)E * 4;
    int* totals   = (int*)(ws + off);   off += 1024;
    unsigned short* WeP = (unsigned short*)(ws + off); off += 4096 * 8 * 2;  // 64 KB

    const int nbE = (E + 255) / 256;
    const int nbN = (N + 255) / 256;

    // ---- CSR build ----
    hipMemsetAsync(cursor, 0, (size_t)N * 4, stream);
    hist_kernel<<<nbE, 256, 0, stream>>>(dst, cursor, E);
    scan_s1<<<nbN, 256, 0, stream>>>(cursor, row_ptr, totals, N);
    scan_s2<<<1, 256, 0, stream>>>(totals, nbN);
    scan_s3<<<nbN, 256, 0, stream>>>(row_ptr, totals, cursor, N, E);
    scatter_kernel<<<nbE, 256, 0, stream>>>(src, dst, cursor, col_src, col_dst, col_eid, E);
    pack_we<<<16, 256, 0, stream>>>(W_e0, W_e1, WeP);

    dim3 ggrid((N + 127) / 128, 4);
    const int ngat = (N + 3) / 4;

    // ---- Layer 0 ----
    gemm_xlxr128<<<ggrid, 256, 0, stream>>>(x, N, 512, W_l0, b_l0, W_r0, b_r0, bufA);
    logit_kernel<<<1024, 256, 0, stream>>>(bufA, edge_attr, col_src, col_dst, col_eid,
                                           WeP, att0, logits, E);
    aggregate_kernel<<<ngat, 256, 0, stream>>>(bufA, logits, col_src, row_ptr, bias0, bufB, N);

    // ---- Layer 1 ----
    gemm_xlxr128<<<ggrid, 256, 0, stream>>>(bufB, N, 256, W_l1, b_l1, W_r1, b_r1, bufA);
    logit_kernel<<<1024, 256, 0, stream>>>(bufA, edge_attr, col_src, col_dst, col_eid,
                                           WeP + 16384, att1, logits, E);
    aggregate_kernel<<<ngat, 256, 0, stream>>>(bufA, logits, col_src, row_ptr, bias1, bufB, N);

    // ---- Output projection ----
    final_out_kernel<<<ngat, 256, 0, stream>>>(bufB, W_out, b_out, (float*)d_out, N);
}

// Round 4
// 1411.733 us; speedup vs baseline: 1.2798x; 1.2798x over previous
//
#include <hip/hip_runtime.h>
#include <hip/hip_bf16.h>

#define NEG_SLOPE 0.2f

typedef __attribute__((ext_vector_type(8))) short bf16x8;
typedef __attribute__((ext_vector_type(4))) float f32x4;

__device__ __forceinline__ unsigned short bf16hi(float v) {
    __hip_bfloat16 h = __float2bfloat16(v);
    return *(unsigned short*)&h;
}
__device__ __forceinline__ float bf16tof(unsigned short u) {
    __hip_bfloat16 h = *(__hip_bfloat16*)&u;
    return __bfloat162float(h);
}

// ---------------------------------------------------------------------------
// CSR build
// ---------------------------------------------------------------------------
__global__ void hist_kernel(const int* __restrict__ dst, int* __restrict__ cnt, int E) {
    int e = blockIdx.x * 256 + threadIdx.x;
    if (e < E) atomicAdd(&cnt[dst[e]], 1);
}

__global__ void scan_s1(const int* __restrict__ cnt, int* __restrict__ excl,
                        int* __restrict__ totals, int N) {
    __shared__ int lds[256];
    int t = threadIdx.x;
    int i = blockIdx.x * 256 + t;
    int v = (i < N) ? cnt[i] : 0;
    lds[t] = v;
    __syncthreads();
    #pragma unroll
    for (int off = 1; off < 256; off <<= 1) {
        int add = (t >= off) ? lds[t - off] : 0;
        __syncthreads();
        lds[t] += add;
        __syncthreads();
    }
    if (i < N) excl[i] = lds[t] - v;
    if (t == 255) totals[blockIdx.x] = lds[255];
}

__global__ void scan_s2(int* __restrict__ totals, int nb) {
    __shared__ int lds[256];
    int t = threadIdx.x;
    int v = (t < nb) ? totals[t] : 0;
    lds[t] = v;
    __syncthreads();
    #pragma unroll
    for (int off = 1; off < 256; off <<= 1) {
        int add = (t >= off) ? lds[t - off] : 0;
        __syncthreads();
        lds[t] += add;
        __syncthreads();
    }
    if (t < nb) totals[t] = lds[t] - v;   // exclusive over block totals
}

__global__ void scan_s3(int* __restrict__ row_ptr, const int* __restrict__ totals,
                        int* __restrict__ cursor, int N, int E) {
    int i = blockIdx.x * 256 + threadIdx.x;
    if (i < N) {
        int v = row_ptr[i] + totals[blockIdx.x];
        row_ptr[i] = v;
        cursor[i] = v;
    }
    if (i == 0) row_ptr[N] = E;
}

__global__ void scatter_kernel(const int* __restrict__ src, const int* __restrict__ dst,
                               int* __restrict__ cursor, int* __restrict__ col_src,
                               int* __restrict__ col_dst, int* __restrict__ col_eid, int E) {
    int e = blockIdx.x * 256 + threadIdx.x;
    if (e < E) {
        int d = dst[e];
        int pos = atomicAdd(&cursor[d], 1);
        col_src[pos] = src[e];
        col_dst[pos] = d;
        col_eid[pos] = e;
    }
}

// ---------------------------------------------------------------------------
// Pack We (fp32 [32,256]) into MFMA A-fragment order, bf16 hi + lo parts.
// WeP layout: [layer][part][tile][lane][8] shorts; layer stride 16384,
// lo part at +8192. A[m=lane&15][k=(lane>>4)*8+j].
// ---------------------------------------------------------------------------
__global__ void pack_we(const float* __restrict__ We0, const float* __restrict__ We1,
                        unsigned short* __restrict__ WeP) {
    int t = blockIdx.x * 256 + threadIdx.x;
    if (t >= 4096) return;
    int layer = t >> 11;
    int part  = (t >> 10) & 1;
    int tile  = (t >> 6) & 15;
    int lane  = t & 63;
    const float* We = layer ? We1 : We0;
    int ch = tile * 16 + (lane & 15);
    int kb = (lane >> 4) * 8;
    union { unsigned short u[8]; uint4 v; } out;
    #pragma unroll
    for (int j = 0; j < 8; ++j) {
        float w = We[(size_t)(kb + j) * 256 + ch];
        unsigned short hi = bf16hi(w);
        out.u[j] = part ? bf16hi(w - bf16tof(hi)) : hi;
    }
    *(uint4*)(WeP + (size_t)t * 8) = out.v;
}

// ---------------------------------------------------------------------------
// Pack W = [Wl | Wr] (fp32 [K,256] each) into MFMA B-frag order, hi+lo bf16.
// Layout: [part(2)][kt(KT)][ntglob(32)][lane(64)][8] shorts.
// B[n=nt*16+(lane&15)][k=kt*32+(lane>>4)*8+j].
// ---------------------------------------------------------------------------
__global__ void pack_w(const float* __restrict__ Wl, const float* __restrict__ Wr,
                       int KT, unsigned short* __restrict__ out) {
    int t = blockIdx.x * 256 + threadIdx.x;
    int per = KT * 2048;             // KT*32*64
    if (t >= 2 * per) return;
    int part = t / per;
    int rem  = t % per;
    int kt   = rem >> 11;
    int nt   = (rem >> 6) & 31;
    int lane = rem & 63;
    int n  = nt * 16 + (lane & 15);
    int kb = kt * 32 + ((lane >> 4) * 8);
    const float* W = (n < 256) ? (Wl + n) : (Wr + (n - 256));
    union { unsigned short u[8]; uint4 v; } o;
    #pragma unroll
    for (int j = 0; j < 8; ++j) {
        float w = W[(size_t)(kb + j) * 256];
        unsigned short hi = bf16hi(w);
        o.u[j] = part ? bf16hi(w - bf16tof(hi)) : hi;
    }
    *(uint4*)(out + (size_t)t * 8) = o.v;
}

// ---------------------------------------------------------------------------
// Split-bf16 MFMA GEMM: C[M,512] = A[M,K] @ [Wl|Wr] + [bl|br], fp32-accurate
// via 3-term hi/lo split. Block = 128 rows x 128 cols, 4 waves; wave handles
// 2 row-tiles x 8 col-tiles. A staged to LDS as hi/lo bf16 frags per K-step.
// ---------------------------------------------------------------------------
__global__ __launch_bounds__(256) void gemm_split(
    const float* __restrict__ A, int M, int K,
    const unsigned short* __restrict__ Bf,   // [2][KT][32][64][8]
    const float* __restrict__ bl, const float* __restrict__ br,
    float* __restrict__ C)
{
    __shared__ unsigned short Af[2][8][64][8];   // 16 KB: [part][mtile][lane][8]
    const int tid  = threadIdx.x;
    const int lane = tid & 63;
    const int w    = tid >> 6;
    const int m0   = blockIdx.x * 128;
    const int n0   = blockIdx.y * 128;
    const int KT   = K >> 5;
    const int ntg0 = n0 >> 4;

    f32x4 acc[2][8];
    #pragma unroll
    for (int i = 0; i < 2; ++i)
        #pragma unroll
        for (int j = 0; j < 8; ++j) acc[i][j] = (f32x4){0.f, 0.f, 0.f, 0.f};

    const size_t partStride = (size_t)KT * 32 * 512;   // shorts

    for (int kt = 0; kt < KT; ++kt) {
        // ---- stage A tile (128x32 fp32 -> hi/lo bf16 frags in LDS) ----
        #pragma unroll
        for (int i = 0; i < 4; ++i) {
            int idx = tid * 4 + i;          // 0..1023 float4s
            int r   = idx >> 3;             // row 0..127
            int kl  = (idx & 7) * 4;        // k_local 0..28
            int gm  = m0 + r;
            float4 v = make_float4(0.f, 0.f, 0.f, 0.f);
            if (gm < M) v = *(const float4*)(A + (size_t)gm * K + kt * 32 + kl);
            unsigned short h0 = bf16hi(v.x), h1 = bf16hi(v.y);
            unsigned short h2 = bf16hi(v.z), h3 = bf16hi(v.w);
            unsigned short l0 = bf16hi(v.x - bf16tof(h0));
            unsigned short l1 = bf16hi(v.y - bf16tof(h1));
            unsigned short l2 = bf16hi(v.z - bf16tof(h2));
            unsigned short l3 = bf16hi(v.w - bf16tof(h3));
            int mt = r >> 4;
            int la = (r & 15) | ((kl >> 3) << 4);
            int j0 = kl & 7;
            *(uint2*)&Af[0][mt][la][j0] =
                make_uint2((unsigned int)h0 | ((unsigned int)h1 << 16),
                           (unsigned int)h2 | ((unsigned int)h3 << 16));
            *(uint2*)&Af[1][mt][la][j0] =
                make_uint2((unsigned int)l0 | ((unsigned int)l1 << 16),
                           (unsigned int)l2 | ((unsigned int)l3 << 16));
        }
        __syncthreads();

        bf16x8 ah0 = *(const bf16x8*)&Af[0][w * 2 + 0][lane][0];
        bf16x8 ah1 = *(const bf16x8*)&Af[0][w * 2 + 1][lane][0];
        bf16x8 al0 = *(const bf16x8*)&Af[1][w * 2 + 0][lane][0];
        bf16x8 al1 = *(const bf16x8*)&Af[1][w * 2 + 1][lane][0];

        const unsigned short* bbase =
            Bf + ((size_t)kt * 32 + ntg0) * 512 + (size_t)lane * 8;
        #pragma unroll
        for (int nt = 0; nt < 8; ++nt) {
            bf16x8 bh  = *(const bf16x8*)(bbase + (size_t)nt * 512);
            bf16x8 blv = *(const bf16x8*)(bbase + partStride + (size_t)nt * 512);
            acc[0][nt] = __builtin_amdgcn_mfma_f32_16x16x32_bf16(ah0, bh,  acc[0][nt], 0, 0, 0);
            acc[1][nt] = __builtin_amdgcn_mfma_f32_16x16x32_bf16(ah1, bh,  acc[1][nt], 0, 0, 0);
            acc[0][nt] = __builtin_amdgcn_mfma_f32_16x16x32_bf16(ah0, blv, acc[0][nt], 0, 0, 0);
            acc[1][nt] = __builtin_amdgcn_mfma_f32_16x16x32_bf16(ah1, blv, acc[1][nt], 0, 0, 0);
            acc[0][nt] = __builtin_amdgcn_mfma_f32_16x16x32_bf16(al0, bh,  acc[0][nt], 0, 0, 0);
            acc[1][nt] = __builtin_amdgcn_mfma_f32_16x16x32_bf16(al1, bh,  acc[1][nt], 0, 0, 0);
        }
        __syncthreads();
    }

    // ---- epilogue: D row=(lane>>4)*4+r, col=lane&15 ----
    const int q  = lane >> 4;
    const int cl = lane & 15;
    #pragma unroll
    for (int mti = 0; mti < 2; ++mti) {
        int gmb = m0 + (w * 2 + mti) * 16 + q * 4;
        #pragma unroll
        for (int nt = 0; nt < 8; ++nt) {
            int col = n0 + nt * 16 + cl;
            float bia = (col < 256) ? bl[col] : br[col - 256];
            #pragma unroll
            for (int r = 0; r < 4; ++r) {
                int gm = gmb + r;
                if (gm < M) C[(size_t)gm * 512 + col] = acc[mti][nt][r] + bia;
            }
        }
    }
}

// ---------------------------------------------------------------------------
// Pass 1: per-edge attention logits [E,4] in CSR slot order.
// One wave handles 16 edges. ea via 3-term hi/lo bf16 MFMA. Hi We-frags in
// registers, lo frags staged to LDS (occupancy).
// ---------------------------------------------------------------------------
__global__ __launch_bounds__(256) void logit_kernel(
    const float* __restrict__ xlxr,       // [N,512]
    const float* __restrict__ edge_attr,  // [E,32]
    const int* __restrict__ col_src,      // [E]
    const int* __restrict__ col_dst,      // [E]
    const int* __restrict__ col_eid,      // [E]
    const unsigned short* __restrict__ WePl, // hi @0, lo @+8192 shorts
    const float* __restrict__ att,        // [256]
    float* __restrict__ logits,           // [E,4]
    int E)
{
    __shared__ unsigned short AloS[16][64][8];   // 16 KB
    const int tid = threadIdx.x;
    #pragma unroll
    for (int i = 0; i < 4; ++i) {
        int idx = tid * 4 + i;                   // 1024 uint4s = 16 KB
        ((uint4*)&AloS[0][0][0])[idx] = ((const uint4*)(WePl + 8192))[idx];
    }
    const int lane  = tid & 63;
    const int q     = lane >> 4;
    const int e_sub = lane & 15;
    const int kb    = q * 8;

    bf16x8 Ahi[16];
    #pragma unroll
    for (int t = 0; t < 16; ++t)
        Ahi[t] = *(const bf16x8*)(WePl + ((size_t)t * 64 + lane) * 8);
    __syncthreads();

    const int gw = blockIdx.x * 4 + (tid >> 6);
    const int nw = gridDim.x * 4;
    const int nb = (E + 15) >> 4;

    for (int b = gw; b < nb; b += nw) {
        const int slot = b * 16 + e_sub;
        const int sc   = min(slot, E - 1);
        const int eid  = col_eid[sc];
        const int srcn = col_src[sc];
        const int dstn = col_dst[sc];

        const float* ap = edge_attr + (size_t)eid * 32 + kb;
        float4 v0 = *(const float4*)ap;
        float4 v1 = *(const float4*)(ap + 4);
        float vv[8] = {v0.x, v0.y, v0.z, v0.w, v1.x, v1.y, v1.z, v1.w};
        union { bf16x8 v; unsigned short u[8]; } bh, bl;
        #pragma unroll
        for (int i = 0; i < 8; ++i) {
            unsigned short h = bf16hi(vv[i]);
            bh.u[i] = h;
            bl.u[i] = bf16hi(vv[i] - bf16tof(h));
        }

        const float* xlp = xlxr + (size_t)srcn * 512 + q * 4;
        const float* xrp = xlxr + (size_t)dstn * 512 + 256 + q * 4;

        float lph[4] = {0.f, 0.f, 0.f, 0.f};
        #pragma unroll
        for (int t = 0; t < 16; ++t) {
            bf16x8 alo = *(const bf16x8*)&AloS[t][lane][0];
            f32x4 acc = {0.f, 0.f, 0.f, 0.f};
            acc = __builtin_amdgcn_mfma_f32_16x16x32_bf16(Ahi[t], bh.v, acc, 0, 0, 0);
            acc = __builtin_amdgcn_mfma_f32_16x16x32_bf16(Ahi[t], bl.v, acc, 0, 0, 0);
            acc = __builtin_amdgcn_mfma_f32_16x16x32_bf16(alo,    bh.v, acc, 0, 0, 0);
            const float4 xl4 = *(const float4*)(xlp + t * 16);
            const float4 xr4 = *(const float4*)(xrp + t * 16);
            const float4 at4 = *(const float4*)(att + t * 16 + q * 4);
            float z0 = acc[0] + xl4.x + xr4.x; z0 = (z0 > 0.f) ? z0 : NEG_SLOPE * z0;
            float z1 = acc[1] + xl4.y + xr4.y; z1 = (z1 > 0.f) ? z1 : NEG_SLOPE * z1;
            float z2 = acc[2] + xl4.z + xr4.z; z2 = (z2 > 0.f) ? z2 : NEG_SLOPE * z2;
            float z3 = acc[3] + xl4.w + xr4.w; z3 = (z3 > 0.f) ? z3 : NEG_SLOPE * z3;
            float s = z0 * at4.x;
            s = fmaf(z1, at4.y, s);
            s = fmaf(z2, at4.z, s);
            s = fmaf(z3, at4.w, s);
            lph[t >> 2] += s;
        }
        #pragma unroll
        for (int h = 0; h < 4; ++h) {
            lph[h] += __shfl_xor(lph[h], 16, 64);
            lph[h] += __shfl_xor(lph[h], 32, 64);
        }
        if (q == 0 && slot < E) {
            float4 o = make_float4(lph[0], lph[1], lph[2], lph[3]);
            *(float4*)(logits + (size_t)slot * 4) = o;
        }
    }
}

// ---------------------------------------------------------------------------
// Pass 2: aggregation. One wave per node, lane owns channels 4l..4l+3.
// ---------------------------------------------------------------------------
__global__ __launch_bounds__(256) void aggregate_kernel(
    const float* __restrict__ xlxr,     // [N,512]
    const float* __restrict__ logits,   // [E,4] CSR order
    const int* __restrict__ col_src,    // [E]
    const int* __restrict__ row_ptr,    // [N+1]
    const float* __restrict__ bias,     // [256]
    float* __restrict__ hout, int N)
{
    const int n = blockIdx.x * 4 + (threadIdx.x >> 6);
    if (n >= N) return;
    const int l = threadIdx.x & 63;
    const int h = l >> 4;
    const int ch0 = l * 4;

    const int e0 = row_ptr[n], e1 = row_ptr[n + 1];

    float mxh = -3.0e38f;
    for (int j = e0; j < e1; ++j)
        mxh = fmaxf(mxh, logits[(size_t)j * 4 + h]);

    float denom = 0.f;
    float4 acc = make_float4(0.f, 0.f, 0.f, 0.f);
    for (int j = e0; j < e1; ++j) {
        const float lh = logits[(size_t)j * 4 + h];
        const float p = __expf(lh - mxh);
        denom += p;
        const int srcn = col_src[j];
        const float4 xl = *(const float4*)(xlxr + (size_t)srcn * 512 + ch0);
        acc.x = fmaf(p, xl.x, acc.x);
        acc.y = fmaf(p, xl.y, acc.y);
        acc.z = fmaf(p, xl.z, acc.z);
        acc.w = fmaf(p, xl.w, acc.w);
    }

    const float inv = (e1 > e0) ? 1.0f / denom : 0.f;
    const float4 b4 = *(const float4*)(bias + ch0);
    float4 o;
    o.x = fmaxf(fmaf(acc.x, inv, b4.x), 0.f);
    o.y = fmaxf(fmaf(acc.y, inv, b4.y), 0.f);
    o.z = fmaxf(fmaf(acc.z, inv, b4.z), 0.f);
    o.w = fmaxf(fmaf(acc.w, inv, b4.w), 0.f);
    *(float4*)(hout + (size_t)n * 256 + ch0) = o;
}

// ---------------------------------------------------------------------------
// Final projection: out[n] = h[n,:] @ W_out + b_out. One wave per node.
// ---------------------------------------------------------------------------
__global__ __launch_bounds__(256) void final_out_kernel(
    const float* __restrict__ h, const float* __restrict__ Wout,
    const float* __restrict__ bout, float* __restrict__ out, int N)
{
    const int wid  = threadIdx.x >> 6;
    const int lane = threadIdx.x & 63;
    const int n = blockIdx.x * 4 + wid;
    if (n >= N) return;
    float s = 0.f;
    #pragma unroll
    for (int q = 0; q < 4; ++q) {
        int cidx = lane + q * 64;
        s = fmaf(h[(size_t)n * 256 + cidx], Wout[cidx], s);
    }
    #pragma unroll
    for (int off = 32; off > 0; off >>= 1)
        s += __shfl_xor(s, off, 64);
    if (lane == 0) out[n] = s + bout[0];
}

// ---------------------------------------------------------------------------
extern "C" void kernel_launch(void* const* d_in, const int* in_sizes, int n_in,
                              void* d_out, int out_size, void* d_ws, size_t ws_size,
                              hipStream_t stream) {
    const float* x         = (const float*)d_in[0];
    const int*   edge_idx  = (const int*)d_in[1];
    const float* edge_attr = (const float*)d_in[2];
    const float* W_l0 = (const float*)d_in[3];
    const float* b_l0 = (const float*)d_in[4];
    const float* W_r0 = (const float*)d_in[5];
    const float* b_r0 = (const float*)d_in[6];
    const float* W_e0 = (const float*)d_in[7];
    const float* att0 = (const float*)d_in[8];
    const float* bias0= (const float*)d_in[9];
    const float* W_l1 = (const float*)d_in[10];
    const float* b_l1 = (const float*)d_in[11];
    const float* W_r1 = (const float*)d_in[12];
    const float* b_r1 = (const float*)d_in[13];
    const float* W_e1 = (const float*)d_in[14];
    const float* att1 = (const float*)d_in[15];
    const float* bias1= (const float*)d_in[16];
    const float* W_out= (const float*)d_in[17];
    const float* b_out= (const float*)d_in[18];

    const int N = in_sizes[0] / 512;      // 50000
    const int E = in_sizes[1] / 2;        // 800000

    const int* src = edge_idx;
    const int* dst = edge_idx + E;

    // workspace layout (~178 MB total)
    char* ws = (char*)d_ws;
    size_t off = 0;
    float* bufA   = (float*)(ws + off); off += (size_t)N * 512 * 4;   // 102.4 MB
    float* bufB   = (float*)(ws + off); off += (size_t)N * 256 * 4;   //  51.2 MB
    float* logits = (float*)(ws + off); off += (size_t)E * 4 * 4;     //  12.8 MB
    int* row_ptr  = (int*)(ws + off);   off += (((size_t)(N + 1) * 4 + 255) & ~(size_t)255);
    int* cursor   = (int*)(ws + off);   off += (((size_t)N * 4 + 255) & ~(size_t)255);
    int* col_src  = (int*)(ws + off);   off += (size_t)E * 4;
    int* col_dst  = (int*)(ws + off);   off += (size_t)E * 4;
    int* col_eid  = (int*)(ws + off);   off += (size_t)E * 4;
    int* totals   = (int*)(ws + off);   off += 1024;
    unsigned short* WeP = (unsigned short*)(ws + off); off += 4096 * 8 * 2;        // 64 KB
    unsigned short* Bf0 = (unsigned short*)(ws + off); off += (size_t)2 * 16 * 32 * 64 * 8 * 2; // 1 MB
    unsigned short* Bf1 = (unsigned short*)(ws + off); off += (size_t)2 * 8 * 32 * 64 * 8 * 2;  // 512 KB

    const int nbE = (E + 255) / 256;
    const int nbN = (N + 255) / 256;

    // ---- CSR build + weight prepack ----
    hipMemsetAsync(cursor, 0, (size_t)N * 4, stream);
    hist_kernel<<<nbE, 256, 0, stream>>>(dst, cursor, E);
    scan_s1<<<nbN, 256, 0, stream>>>(cursor, row_ptr, totals, N);
    scan_s2<<<1, 256, 0, stream>>>(totals, nbN);
    scan_s3<<<nbN, 256, 0, stream>>>(row_ptr, totals, cursor, N, E);
    scatter_kernel<<<nbE, 256, 0, stream>>>(src, dst, cursor, col_src, col_dst, col_eid, E);
    pack_we<<<16, 256, 0, stream>>>(W_e0, W_e1, WeP);
    pack_w<<<256, 256, 0, stream>>>(W_l0, W_r0, 16, Bf0);
    pack_w<<<128, 256, 0, stream>>>(W_l1, W_r1, 8, Bf1);

    dim3 ggrid((N + 127) / 128, 4);
    const int ngat = (N + 3) / 4;

    // ---- Layer 0 ----
    gemm_split<<<ggrid, 256, 0, stream>>>(x, N, 512, Bf0, b_l0, b_r0, bufA);
    logit_kernel<<<2048, 256, 0, stream>>>(bufA, edge_attr, col_src, col_dst, col_eid,
                                           WeP, att0, logits, E);
    aggregate_kernel<<<ngat, 256, 0, stream>>>(bufA, logits, col_src, row_ptr, bias0, bufB, N);

    // ---- Layer 1 ----
    gemm_split<<<ggrid, 256, 0, stream>>>(bufB, N, 256, Bf1, b_l1, b_r1, bufA);
    logit_kernel<<<2048, 256, 0, stream>>>(bufA, edge_attr, col_src, col_dst, col_eid,
                                           WeP + 16384, att1, logits, E);
    aggregate_kernel<<<ngat, 256, 0, stream>>>(bufA, logits, col_src, row_ptr, bias1, bufB, N);

    // ---- Output projection ----
    final_out_kernel<<<ngat, 256, 0, stream>>>(bufB, W_out, b_out, (float*)d_out, N);
}